// Round 1
// 637.052 us; speedup vs baseline: 1.0204x; 1.0204x over previous
//
#include <hip/hip_runtime.h>

#define Bb 2
#define Ss 2048
#define Dd 1024
#define Hh 16
#define HD 64
#define Mm (Bb*Ss)   // 4096

typedef __bf16 bf16;
typedef __bf16 bf16x8 __attribute__((ext_vector_type(8)));
typedef float f32x4 __attribute__((ext_vector_type(4)));

// async global->LDS, 16B per lane; dest must be wave-uniform base + lane*16 (linear)
__device__ __forceinline__ void gload_lds16(const bf16* g, bf16* l) {
    __builtin_amdgcn_global_load_lds(
        (const __attribute__((address_space(1))) unsigned int*)g,
        (__attribute__((address_space(3))) unsigned int*)l,
        16, 0, 0);
}

// ---------------- prep: fp32 -> bf16 cast ----------------
__global__ void cvt_f32_bf16(const float* __restrict__ in, bf16* __restrict__ out, int n4) {
    int i = blockIdx.x * blockDim.x + threadIdx.x;
    if (i < n4) {
        float4 v = *(const float4*)(in + i * 4);
        out[i*4+0] = (bf16)v.x; out[i*4+1] = (bf16)v.y;
        out[i*4+2] = (bf16)v.z; out[i*4+3] = (bf16)v.w;
    }
}

// ---------------- prep: W [K,N] fp32 -> Wt [N,K] bf16 ----------------
__global__ void wtrans(const float* __restrict__ W0, const float* __restrict__ W1,
                       const float* __restrict__ W2, const float* __restrict__ W3,
                       bf16* __restrict__ O0, bf16* __restrict__ O1,
                       bf16* __restrict__ O2, bf16* __restrict__ O3) {
    const float* W = (blockIdx.z == 0) ? W0 : (blockIdx.z == 1) ? W1 : (blockIdx.z == 2) ? W2 : W3;
    bf16* O = (blockIdx.z == 0) ? O0 : (blockIdx.z == 1) ? O1 : (blockIdx.z == 2) ? O2 : O3;
    __shared__ bf16 t[64][65];
    int k0 = blockIdx.x * 64, n0 = blockIdx.y * 64;
    for (int c = threadIdx.x; c < 4096; c += 256) {
        int r = c >> 6, cc = c & 63;
        t[r][cc] = (bf16)W[(k0 + r) * Dd + n0 + cc];
    }
    __syncthreads();
    for (int c = threadIdx.x; c < 4096; c += 256) {
        int r = c >> 6, cc = c & 63;
        O[(n0 + r) * Dd + k0 + cc] = t[cc][r];
    }
}

// ---------------- GEMM: C[M,N] = A[M,K] * Bt[N,K]^T + bias ----------------
// 128x128 tile, BK=32, 4 waves. Staging via global_load_lds width 16 (m97 structure).
// mode 0: out o0[m*1024+n] (+b0). mode 1: fused QKV, Bt = [WqT;WkT;WvT] (3072x1024),
//         n selects {o0,o1,o2}/{b0,b1,b2}, output in [B,H,S,HD] split-head layout.
__global__ __launch_bounds__(256, 3)
void gemm_bt(const bf16* __restrict__ A, const bf16* __restrict__ Bt,
             const float* __restrict__ b0, const float* __restrict__ b1, const float* __restrict__ b2,
             bf16* __restrict__ o0, bf16* __restrict__ o1, bf16* __restrict__ o2, int mode) {
    const int K = 1024;
    __shared__ __align__(16) bf16 As[128 * 32];
    __shared__ __align__(16) bf16 Bs[128 * 32];
    int tid = threadIdx.x;
    int wave = tid >> 6, lane = tid & 63;
    int lane15 = lane & 15, quad = lane >> 4;
    int wm = (wave >> 1) * 64, wn = (wave & 1) * 64;
    int m0 = blockIdx.x * 128, n0 = blockIdx.y * 128;
    // staging map: lane covers (row = wave*16 + lane>>2, cols (lane&3)*8..+8)
    int lrow = lane >> 2, lcol = (lane & 3) * 8;
    const bf16* Ag = &A[(size_t)(m0 + wave * 16 + lrow) * K + lcol];
    const bf16* Bg = &Bt[(size_t)(n0 + wave * 16 + lrow) * K + lcol];
    bf16* Asw = &As[wave * 16 * 32];
    bf16* Bsw = &Bs[wave * 16 * 32];

    f32x4 acc[4][4] = {};

    for (int kt = 0; kt < K; kt += 32) {
        __syncthreads();
        gload_lds16(Ag + kt,           Asw);
        gload_lds16(Ag + 64 * K + kt,  Asw + 64 * 32);
        gload_lds16(Bg + kt,           Bsw);
        gload_lds16(Bg + 64 * K + kt,  Bsw + 64 * 32);
        __syncthreads();   // compiler drains vmcnt before barrier
        bf16x8 af[4], bfr[4];
#pragma unroll
        for (int i = 0; i < 4; i++) af[i] = *(const bf16x8*)(&As[(wm + i * 16 + lane15) * 32 + quad * 8]);
#pragma unroll
        for (int j = 0; j < 4; j++) bfr[j] = *(const bf16x8*)(&Bs[(wn + j * 16 + lane15) * 32 + quad * 8]);
#pragma unroll
        for (int i = 0; i < 4; i++)
#pragma unroll
            for (int j = 0; j < 4; j++)
                acc[i][j] = __builtin_amdgcn_mfma_f32_16x16x32_bf16(af[i], bfr[j], acc[i][j], 0, 0, 0);
    }

#pragma unroll
    for (int i = 0; i < 4; i++) {
        int mbase = m0 + wm + i * 16 + quad * 4;
#pragma unroll
        for (int j = 0; j < 4; j++) {
            int n = n0 + wn + j * 16 + lane15;
            if (mode == 0) {
                float bv = b0[n];
#pragma unroll
                for (int r = 0; r < 4; r++)
                    o0[(size_t)(mbase + r) * 1024 + n] = (bf16)(acc[i][j][r] + bv);
            } else {
                int which = n >> 10, nn = n & 1023;
                const float* bp = (which == 0) ? b0 : (which == 1) ? b1 : b2;
                bf16* op = (which == 0) ? o0 : (which == 1) ? o1 : o2;
                float bv = bp[nn];
                int hh = nn >> 6, hd = nn & 63;
#pragma unroll
                for (int r = 0; r < 4; r++) {
                    int m = mbase + r;
                    int bb = m >> 11, s = m & 2047;
                    op[(((size_t)(bb * Hh + hh) * Ss + s) * HD) + hd] = (bf16)(acc[i][j][r] + bv);
                }
            }
        }
    }
}

// ---------------- flash attention ----------------
// grid: (qt=32, h=16, b=2), 256 threads (4 waves). Wave w owns q rows [qt*64+w*16, +16).
// LDS tiles XOR-swizzled to kill the 128B-row-stride bank conflicts:
//   Ks/QPs: col ^= (row&7)*8   (write side vectorized/cheap, read side balanced)
//   Vts   : col ^= ((d&7)^((d>>3)&7))*8  (spreads BOTH transpose-scatter writes and b128 reads)
//   Als   : col ^= ((r>>2)&1)*16 + ((r>>3)&1)*8 (fp32, quad-aware)
// Q and P share one LDS tile (Q is register-hoisted before the loop) -> 40KB/block = 4 blocks/CU.
__global__ __launch_bounds__(256, 4)
void attn_kernel(const bf16* __restrict__ Q, const bf16* __restrict__ Kk, const bf16* __restrict__ V,
                 const float* __restrict__ alibi, const float* __restrict__ mask,
                 bf16* __restrict__ outattn) {
    int qt = blockIdx.x, h = blockIdx.y, b = blockIdx.z;
    __shared__ __align__(16) bf16 Ks[64 * 64];
    __shared__ __align__(16) bf16 Vts[64 * 64];
    __shared__ __align__(16) bf16 QPs[64 * 64];
    __shared__ __align__(16) float Als[64 * 64];
    int tid = threadIdx.x, wave = tid >> 6, lane = tid & 63;
    int lane15 = lane & 15, quad = lane >> 4;

    const bf16* Qbase = Q + ((size_t)(b * Hh + h) * Ss + qt * 64) * HD;
    const bf16* Kbase = Kk + (size_t)(b * Hh + h) * Ss * HD;
    const bf16* Vbase = V + (size_t)(b * Hh + h) * Ss * HD;
    const float* Abase = alibi + ((size_t)h * Ss + qt * 64) * Ss;
    const float* mask_base = mask + (size_t)b * Ss;

    for (int c = tid; c < 512; c += 256) {
        int r = c >> 3, off = (c & 7) * 8;
        *(bf16x8*)(&QPs[r * 64 + (off ^ ((r & 7) * 8))]) = *(const bf16x8*)(&Qbase[r * HD + off]);
    }
    __syncthreads();
    int qrow = wave * 16 + lane15;
    bf16x8 qf0 = *(const bf16x8*)(&QPs[qrow * 64 + ((quad * 8) ^ ((qrow & 7) * 8))]);
    bf16x8 qf1 = *(const bf16x8*)(&QPs[qrow * 64 + ((32 + quad * 8) ^ ((qrow & 7) * 8))]);

    float m_i[4], l_i[4];
    f32x4 O[4] = {};
#pragma unroll
    for (int r = 0; r < 4; r++) { m_i[r] = -1e30f; l_i[r] = 0.f; }

    const float scale = 0.125f;  // HD^-0.5

    for (int kt = 0; kt < Ss; kt += 64) {
        __syncthreads();
        for (int c = tid; c < 512; c += 256) {
            int r = c >> 3, off = (c & 7) * 8;
            *(bf16x8*)(&Ks[r * 64 + (off ^ ((r & 7) * 8))]) = *(const bf16x8*)(&Kbase[(size_t)(kt + r) * HD + off]);
        }
        for (int c = tid; c < 512; c += 256) {
            int r = c >> 3, off = (c & 7) * 8;
            bf16x8 v = *(const bf16x8*)(&Vbase[(size_t)(kt + r) * HD + off]);
#pragma unroll
            for (int e = 0; e < 8; e++) {
                int d = off + e;
                Vts[d * 64 + (r ^ ((((d & 7) ^ ((d >> 3) & 7))) * 8))] = v[e];
            }
        }
        for (int c = tid; c < 1024; c += 256) {
            int r = c >> 4, c4 = (c & 15) * 4;
            *(float4*)(&Als[r * 64 + (c4 ^ (((r >> 2) & 1) * 16 + ((r >> 3) & 1) * 8))]) =
                *(const float4*)(&Abase[(size_t)r * Ss + kt + c4]);
        }
        __syncthreads();

        f32x4 sc[4];
        f32x4 z = {0.f, 0.f, 0.f, 0.f};
#pragma unroll
        for (int j = 0; j < 4; j++) {
            int krow = j * 16 + lane15;
            bf16x8 kf0 = *(const bf16x8*)(&Ks[krow * 64 + ((quad * 8) ^ ((krow & 7) * 8))]);
            bf16x8 kf1 = *(const bf16x8*)(&Ks[krow * 64 + ((32 + quad * 8) ^ ((krow & 7) * 8))]);
            f32x4 s = __builtin_amdgcn_mfma_f32_16x16x32_bf16(qf0, kf0, z, 0, 0, 0);
            s = __builtin_amdgcn_mfma_f32_16x16x32_bf16(qf1, kf1, s, 0, 0, 0);
            sc[j] = s;
        }
#pragma unroll
        for (int j = 0; j < 4; j++) {
            int col = j * 16 + lane15;
            float mk = mask_base[kt + col];
#pragma unroll
            for (int r = 0; r < 4; r++) {
                int row = wave * 16 + quad * 4 + r;
                float al = Als[row * 64 + (col ^ (((row >> 2) & 1) * 16 + ((row >> 3) & 1) * 8))];
                sc[j][r] = sc[j][r] * scale + al + mk;
            }
        }
        float alpha[4];
#pragma unroll
        for (int r = 0; r < 4; r++) {
            float v = fmaxf(fmaxf(sc[0][r], sc[1][r]), fmaxf(sc[2][r], sc[3][r]));
#pragma unroll
            for (int d = 1; d < 16; d <<= 1) v = fmaxf(v, __shfl_xor(v, d, 64));
            float mnew = fmaxf(m_i[r], v);
            alpha[r] = __expf(m_i[r] - mnew);
            m_i[r] = mnew;
        }
        float rs[4] = {0.f, 0.f, 0.f, 0.f};
#pragma unroll
        for (int j = 0; j < 4; j++)
#pragma unroll
            for (int r = 0; r < 4; r++) {
                float p = __expf(sc[j][r] - m_i[r]);
                sc[j][r] = p;
                rs[r] += p;
            }
#pragma unroll
        for (int r = 0; r < 4; r++) {
            float v = rs[r];
#pragma unroll
            for (int d = 1; d < 16; d <<= 1) v += __shfl_xor(v, d, 64);
            l_i[r] = l_i[r] * alpha[r] + v;
        }
#pragma unroll
        for (int j = 0; j < 4; j++)
#pragma unroll
            for (int r = 0; r < 4; r++) {
                int row = wave * 16 + quad * 4 + r;
                QPs[row * 64 + ((j * 16 + lane15) ^ ((row & 7) * 8))] = (bf16)sc[j][r];
            }
        __syncthreads();

        int prow = wave * 16 + lane15;
        bf16x8 pf0 = *(const bf16x8*)(&QPs[prow * 64 + ((quad * 8) ^ ((prow & 7) * 8))]);
        bf16x8 pf1 = *(const bf16x8*)(&QPs[prow * 64 + ((32 + quad * 8) ^ ((prow & 7) * 8))]);
#pragma unroll
        for (int jd = 0; jd < 4; jd++) {
            int vrow = jd * 16 + lane15;
            int vs = (((vrow & 7) ^ ((vrow >> 3) & 7)) * 8);
#pragma unroll
            for (int r = 0; r < 4; r++) O[jd][r] *= alpha[r];
            bf16x8 vf0 = *(const bf16x8*)(&Vts[vrow * 64 + ((quad * 8) ^ vs)]);
            bf16x8 vf1 = *(const bf16x8*)(&Vts[vrow * 64 + ((32 + quad * 8) ^ vs)]);
            O[jd] = __builtin_amdgcn_mfma_f32_16x16x32_bf16(pf0, vf0, O[jd], 0, 0, 0);
            O[jd] = __builtin_amdgcn_mfma_f32_16x16x32_bf16(pf1, vf1, O[jd], 0, 0, 0);
        }
    }

#pragma unroll
    for (int jd = 0; jd < 4; jd++) {
        int d = jd * 16 + lane15;
#pragma unroll
        for (int r = 0; r < 4; r++) {
            int qg = qt * 64 + wave * 16 + quad * 4 + r;
            float v = O[jd][r] / l_i[r];
            outattn[(((size_t)b * Ss + qg) * Hh + h) * HD + d] = (bf16)v;
        }
    }
}

// ---------------- residual + layernorm ----------------
__global__ void ln_kernel(const float* __restrict__ hidden, const bf16* __restrict__ Y,
                          const float* __restrict__ gamma, const float* __restrict__ beta,
                          float* __restrict__ out) {
    int row = blockIdx.x;
    int tid = threadIdx.x, wave = tid >> 6, lane = tid & 63;
    float x[4];
    float s = 0.f, q = 0.f;
#pragma unroll
    for (int e = 0; e < 4; e++) {
        int col = e * 256 + tid;
        x[e] = hidden[(size_t)row * Dd + col] + (float)Y[(size_t)row * Dd + col];
        s += x[e];
        q += x[e] * x[e];
    }
#pragma unroll
    for (int d = 1; d < 64; d <<= 1) { s += __shfl_xor(s, d, 64); q += __shfl_xor(q, d, 64); }
    __shared__ float sm[4], sq[4];
    if (lane == 0) { sm[wave] = s; sq[wave] = q; }
    __syncthreads();
    float tot = sm[0] + sm[1] + sm[2] + sm[3];
    float totq = sq[0] + sq[1] + sq[2] + sq[3];
    float mu = tot * (1.f / 1024.f);
    float var = totq * (1.f / 1024.f) - mu * mu;
    float rstd = rsqrtf(var + 1e-12f);
#pragma unroll
    for (int e = 0; e < 4; e++) {
        int col = e * 256 + tid;
        out[(size_t)row * Dd + col] = (x[e] - mu) * rstd * gamma[col] + beta[col];
    }
}

// ---------------- launch ----------------
extern "C" void kernel_launch(void* const* d_in, const int* in_sizes, int n_in,
                              void* d_out, int out_size, void* d_ws, size_t ws_size,
                              hipStream_t stream) {
    const float* hidden = (const float*)d_in[0];
    const float* amask  = (const float*)d_in[1];
    const float* alibi  = (const float*)d_in[2];
    const float* Wq = (const float*)d_in[3];
    const float* bq = (const float*)d_in[4];
    const float* Wk = (const float*)d_in[5];
    const float* bk = (const float*)d_in[6];
    const float* Wv = (const float*)d_in[7];
    const float* bv = (const float*)d_in[8];
    const float* Wo = (const float*)d_in[9];
    const float* bo = (const float*)d_in[10];
    const float* ln_g = (const float*)d_in[11];
    const float* ln_b = (const float*)d_in[12];
    float* out = (float*)d_out;

    char* w = (char*)d_ws;
    bf16* Xb   = (bf16*)(w);                       // 4096x1024      8,388,608 B
    bf16* WqT  = (bf16*)(w + 8388608);             // [WqT;WkT;WvT] contiguous 3072x1024
    bf16* WkT  = (bf16*)(w + 10485760);
    bf16* WvT  = (bf16*)(w + 12582912);
    bf16* WoT  = (bf16*)(w + 14680064);
    bf16* Qw   = (bf16*)(w + 16777216);            // [B,H,S,HD]     8,388,608 B
    bf16* Kw   = (bf16*)(w + 25165824);
    bf16* Vw   = (bf16*)(w + 33554432);
    bf16* Attn = (bf16*)(w + 41943040);            // [B,S,H,HD] = [4096,1024]
    bf16* Yw   = (bf16*)(w + 50331648);            // [4096,1024]

    cvt_f32_bf16<<<4096, 256, 0, stream>>>(hidden, Xb, Mm * Dd / 4);
    wtrans<<<dim3(16, 16, 4), 256, 0, stream>>>(Wq, Wk, Wv, Wo, WqT, WkT, WvT, WoT);

    // fused QKV GEMM: Bt = [WqT;WkT;WvT] (3072 rows), grid 32x24 = 768 blocks = 3/CU
    gemm_bt<<<dim3(32, 24), 256, 0, stream>>>(Xb, WqT, bq, bk, bv, Qw, Kw, Vw, 1);

    attn_kernel<<<dim3(32, 16, 2), 256, 0, stream>>>(Qw, Kw, Vw, alibi, amask, Attn);

    gemm_bt<<<dim3(32, 8), 256, 0, stream>>>(Attn, WoT, bo, nullptr, nullptr, Yw, nullptr, nullptr, 0);

    ln_kernel<<<4096, 256, 0, stream>>>(hidden, Yw, ln_g, ln_b, out);
}